// Round 8
// baseline (351.550 us; speedup 1.0000x reference)
//
#include <hip/hip_runtime.h>
#include <math.h>

// MMD, Gaussian kernel, bandwidth=512. X:[8192,512] Y:[8192,512] fp32.
// S_AB = sum_ij exp(-||a_i-b_j||^2/512); final combine emulates the
// reference's fp32 logsumexp->exp->combine path (see finalize_kernel).
//
// Architecture (validated R9-R11): fp16 single-product MFMA S-pass (S needs
// << 1 fp32 lse cell) + bit-exact R5 bf16-split 3-product d2 min for m
// (XX/YY via 32x32 diag self-tiles, XY via banded refine).
// R15/R18 (PASSED, ~180us): 128x128 tiles, A+B DMA-staged; 2-barrier and
// 1-barrier/3-buffer schedules both land at MfmaUtil ~34-37%, ~180us.
// Three structures, three occupancies -> all pinned: this is the documented
// m97-structure ceiling (no BW at roofline: LDS ~57 B/cyc/CU of 112, L2 33%,
// HBM 6.5%). The verified escape is the 256^2 8-phase schedule.
// Round-20 (this): 256x256 tile, 512 thr / 8 waves (2x4), per-wave 128x64
// acc[4][2]; BK=64; 2x64KB LDS dbuf (kstep-major fragment layout, measured
// conflict-free). Phase = 1 kstep: {issue 2 DMAs (kt+1, ksp) -> vmcnt(8) ->
// s_barrier -> 6 ds_read_b128 -> lgkmcnt(0) -> setprio(1) -> 8 MFMA ->
// setprio(0)}. Ledger: kt ksp's pair always has exactly 8 younger DMAs ->
// constant vmcnt(8) in-loop (never 0); kt=7 tail 6/4/2/0. Homogeneous DMA
// window (norm loads drained in prologue - R16 lesson). Buffer reuse safe:
// within any barrier segment, DMA writes and ds_reads never touch the same
// buffer+kstep region. Each C-cell's MFMA k-chain stays ks0..31 sequential
// with identical fragments -> per-cell d2 bits unchanged; only double-sum
// grouping changes (tolerance-validated R15). bmin coarsens to 256-blocks;
// refine gates on bmin[(bi>>1)*32+bj] <= old gate -> superset of tiles
// refined -> identical final m bits.

#define D      512
#define BTM    128   // refine-kernel row tile
#define BTN    256   // refine-kernel col tile
#define BM2    256   // pair-kernel tile rows
#define BN2    256   // pair-kernel tile cols
#define BK     16
#define KSTEPS (D / BK)

// 16B-unit offsets in the XY refine kernel's LDS (R5 layout [point*2+khalf])
#define AHI 0
#define ALO 256
#define BHI 512
#define BLO 1024

typedef _Float16 half8 __attribute__((ext_vector_type(8)));
typedef __attribute__((ext_vector_type(8)))  short  short8;   // 8 bf16
typedef __attribute__((ext_vector_type(16))) float  f32x16;   // 32x32 acc

union U4H8 { uint4 u; half8 h; };
union U4S8 { uint4 u; short8 s; };

__device__ __forceinline__ unsigned short bf16_rne(float x) {
    unsigned u = __float_as_uint(x);
    return (unsigned short)((u + 0x7fffu + ((u >> 16) & 1u)) >> 16);
}
__device__ __forceinline__ float bf16_f32(unsigned short b) {
    return __uint_as_float(((unsigned)b) << 16);
}
__device__ __forceinline__ void split8(const float v[8], uint4& hi, uint4& lo) {
    unsigned h[8], l[8];
    #pragma unroll
    for (int j = 0; j < 8; j++) {
        unsigned short bh = bf16_rne(v[j]);
        float r = v[j] - bf16_f32(bh);          // exact (Sterbenz)
        unsigned short bl = bf16_rne(r);
        h[j] = bh; l[j] = bl;
    }
    hi.x = h[0] | (h[1] << 16); hi.y = h[2] | (h[3] << 16);
    hi.z = h[4] | (h[5] << 16); hi.w = h[6] | (h[7] << 16);
    lo.x = l[0] | (l[1] << 16); lo.y = l[2] | (l[3] << 16);
    lo.z = l[4] | (l[5] << 16); lo.w = l[6] | (l[7] << 16);
}

// async global->LDS, 16B per lane
__device__ __forceinline__ void lds16(const uint4* g, uint4* l) {
    __builtin_amdgcn_global_load_lds(
        (const __attribute__((address_space(1))) void*)g,
        (__attribute__((address_space(3))) void*)(unsigned int)(uintptr_t)(void*)l,
        16, 0, 0);
}

__global__ void init_kernel(double* accum, unsigned* minkey) {
    if (threadIdx.x < 3) accum[threadIdx.x] = 0.0;
    if (threadIdx.x < 4) minkey[threadIdx.x] = 0xFFFFFFFFu;
}

// fp16 convert: src[npts][512] fp32 -> [kstep][p>>5][khalf][p&31] 16B units
__global__ __launch_bounds__(256)
void convert_h_kernel(const float* __restrict__ X, const float* __restrict__ Y,
                      uint4* __restrict__ Xh, uint4* __restrict__ Yh, int npts) {
    const float* src = blockIdx.z ? Y : X;
    uint4*       dst = blockIdx.z ? Yh : Xh;
    const int ks = blockIdx.y;
    const int p  = blockIdx.x * 256 + threadIdx.x;
    if (p >= npts) return;
    const float* s = src + (size_t)p * D + ks * BK;
    float v[16];
    *(float4*)&v[0]  = *(const float4*)(s);
    *(float4*)&v[4]  = *(const float4*)(s + 4);
    *(float4*)&v[8]  = *(const float4*)(s + 8);
    *(float4*)&v[12] = *(const float4*)(s + 12);
    U4H8 a, b;
    #pragma unroll
    for (int j = 0; j < 8; j++) { a.h[j] = (_Float16)v[j]; b.h[j] = (_Float16)v[8 + j]; }
    size_t u = (size_t)ks * npts * 2 + (size_t)(p >> 5) * 64 + (p & 31);
    dst[u] = a.u; dst[u + 32] = b.u;
}

__global__ __launch_bounds__(256)
void row_norms_kernel(const float* __restrict__ X, const float* __restrict__ Y,
                      float* __restrict__ X2, float* __restrict__ Y2, int N, int M) {
    const int wave = threadIdx.x >> 6;
    const int lane = threadIdx.x & 63;
    const int row  = blockIdx.x * 4 + wave;
    const float* src; float* dst; int r;
    if (row < N)          { src = X; dst = X2; r = row; }
    else if (row < N + M) { src = Y; dst = Y2; r = row - N; }
    else return;
    const float* p = src + (size_t)r * D;
    float s = 0.f;
    #pragma unroll
    for (int c = 0; c < D; c += 64) {
        float v = p[c + lane];
        s = fmaf(v, v, s);
    }
    #pragma unroll
    for (int off = 32; off > 0; off >>= 1) s += __shfl_down(s, off);
    if (lane == 0) dst[r] = s;
}

__device__ inline unsigned float_key(float f) {
    unsigned u = __float_as_uint(f);
    return (u & 0x80000000u) ? ~u : (u | 0x80000000u);
}
__device__ inline float key_float(unsigned k) {
    return __uint_as_float((k & 0x80000000u) ? (k ^ 0x80000000u) : ~k);
}

// ---- XX/YY m: R5-bit-exact diag d2 via 32x32 self-tiles (fused X+Y) ------
__global__ __launch_bounds__(256)
void diag_min_bits_kernel(const float* __restrict__ X, const float* __restrict__ Y,
                          const float* __restrict__ X2, const float* __restrict__ Y2,
                          unsigned* __restrict__ minkey, int ngx) {
    int b = blockIdx.x;
    const float *src, *n2; int zidx;
    if (b < ngx) { src = X; n2 = X2; zidx = 0; }
    else         { src = Y; n2 = Y2; zidx = 2; b -= ngx; }

    const int tid  = threadIdx.x;
    const int wave = tid >> 6, lane = tid & 63;
    const int grp  = b * 4 + wave;                // 32-point group id
    const int fp   = lane & 31, fh = lane >> 5;
    const int pt   = grp * 32 + fp;
    const float* s = src + (size_t)pt * D + fh * 8;

    f32x16 acc;
    #pragma unroll
    for (int i = 0; i < 16; i++) acc[i] = 0.f;

    for (int ks = 0; ks < KSTEPS; ks++) {
        float v[8];
        *(float4*)&v[0] = *(const float4*)(s + ks * BK);
        *(float4*)&v[4] = *(const float4*)(s + ks * BK + 4);
        U4S8 hi, lo;
        split8(v, hi.u, lo.u);
        short8 ah = hi.s, al = lo.s;
        // R5 order: hh, h*lB, lA*h (A-frag == B-frag here)
        acc = __builtin_amdgcn_mfma_f32_32x32x16_bf16(ah, ah, acc, 0, 0, 0);
        acc = __builtin_amdgcn_mfma_f32_32x32x16_bf16(ah, al, acc, 0, 0, 0);
        acc = __builtin_amdgcn_mfma_f32_32x32x16_bf16(al, ah, acc, 0, 0, 0);
    }

    float dmin = 1e30f;
    if (fh == ((fp >> 2) & 1)) {
        int r = (fp & 3) + 4 * (fp >> 3);
        float av = acc[r];
        float rn = n2[pt];
        float cn = rn;
        float d2 = rn + cn - 2.0f * av;           // exact: contraction-safe
        dmin = d2;
    }
    #pragma unroll
    for (int off = 32; off > 0; off >>= 1) dmin = fminf(dmin, __shfl_down(dmin, off));
    __shared__ float wm[4];
    __shared__ int   wz[4];
    if (lane == 0) { wm[wave] = dmin; wz[wave] = zidx; }
    __syncthreads();
    if (tid == 0)
        atomicMin(&minkey[wz[0]],
                  float_key(fminf(fminf(wm[0], wm[1]), fminf(wm[2], wm[3]))));
}

// ---------- fp16 S-pass: grid (32,32,3): z=0 XX (sym), 1 XY, 2 YY ----------
// 256x256 tile, 512 thr / 8 waves (wy=wave>>2 in {0,1}, wx=wave&3), per-wave
// 128x64: acc[4][2]. LDS: 2 bufs x [4 ksteps][A 512u | B 512u] = 2x64 KB.
// 8-phase-style schedule, 1 phase = 1 kstep (4 phases/K-tile, 8 K-tiles):
//   { stage (kt+1, ksp): 2 DMAs ; vmcnt(8) ; s_barrier ; ds_read 4A+2B ;
//     lgkmcnt(0) ; setprio(1) ; 8 MFMA ; setprio(0) }
// Counted window: kt ksp's 2 DMAs always have exactly 8 younger -> vmcnt(8)
// constant in-loop; kt7 tail 6/4/2/0. Norm loads drained in prologue so the
// DMA window stays homogeneous.
__global__ __launch_bounds__(512, 2)
void pair_exp_sum_kernel(const uint4* __restrict__ Xh, const uint4* __restrict__ Yh,
                         const float* __restrict__ X2, const float* __restrict__ Y2,
                         double* __restrict__ accum, float* __restrict__ bmin,
                         int N, int M) {
    const int z = blockIdx.z;
    const uint4 *Ah, *Bh; const float *An, *Bn; bool sym; int na, nb;
    if (z == 0)      { Ah = Xh; Bh = Xh; An = X2; Bn = X2; sym = true;  na = N; nb = N; }
    else if (z == 1) { Ah = Xh; Bh = Yh; An = X2; Bn = Y2; sym = false; na = N; nb = M; }
    else             { Ah = Yh; Bh = Yh; An = Y2; Bn = Y2; sym = true;  na = M; nb = M; }
    const int bi = blockIdx.x, bj = blockIdx.y;
    if (sym && bj < bi) return;                  // whole block below diagonal

    __shared__ uint4  smem[2][4096];             // 2 bufs x 64 KB (4 ksteps each)
    __shared__ float  smN[BM2 + BN2];
    __shared__ double wsum[8];
    __shared__ float  wmin[8];

    const int tid  = threadIdx.x;
    const int wave = tid >> 6, lane = tid & 63;
    const int wy = wave >> 2, wx = wave & 3;     // 2x4 waves, each 128x64
    const int row0 = bi * BM2, col0 = bj * BN2;

    // norms: global->reg, drain (keeps the DMA vmcnt window homogeneous),
    // then reg->LDS. Nothing reads smN until the epilogue.
    float nval = (tid < BM2) ? An[row0 + tid] : Bn[col0 + tid - BM2];
    asm volatile("s_waitcnt vmcnt(0)" ::: "memory");
    smN[tid] = nval;

    const size_t strideA = (size_t)na * 2;       // 16B units per kstep
    const size_t strideB = (size_t)nb * 2;
    const uint4* gA = Ah + (size_t)(row0 >> 5) * 64 + wave * 64 + lane;
    const uint4* gB = Bh + (size_t)(col0 >> 5) * 64 + wave * 64 + lane;

    f32x16 acc[4][2];
    #pragma unroll
    for (int g = 0; g < 4; g++)
        #pragma unroll
        for (int c = 0; c < 2; c++)
            #pragma unroll
            for (int i = 0; i < 16; i++) acc[g][c][i] = 0.f;

    // stage kstep p of K-tile ktn into buffer buf: this wave's 64-unit chunk
    // of A and of B -> exactly 2 DMAs per wave per phase.
    auto stage1 = [&](int buf, int p, int ktn) {
        const int ksg = ktn * 4 + p;
        lds16(gA + (size_t)ksg * strideA, &smem[buf][p * 1024 + wave * 64 + lane]);
        lds16(gB + (size_t)ksg * strideB, &smem[buf][p * 1024 + 512 + wave * 64 + lane]);
    };

    // prologue: stage K-tile 0 fully (8 DMAs/wave in flight)
    #pragma unroll
    for (int p = 0; p < 4; p++) stage1(0, p, 0);

    for (int kt = 0; kt < 7; kt++) {             // K-tiles with a successor
        const int pb = kt & 1, nbuf = pb ^ 1;
        #pragma unroll
        for (int p = 0; p < 4; p++) {
            stage1(nbuf, p, kt + 1);             // 2 DMAs (kt+1, ksp)
            asm volatile("s_waitcnt vmcnt(8)" ::: "memory");  // my (kt,ksp) landed
            __builtin_amdgcn_s_barrier();                     // everyone's
            __builtin_amdgcn_sched_barrier(0);
            const half8* base = (const half8*)&smem[pb][p * 1024];
            half8 ah[4], bh[2];
            #pragma unroll
            for (int g = 0; g < 4; g++) ah[g] = base[(4 * wy + g) * 64 + lane];
            #pragma unroll
            for (int c = 0; c < 2; c++) bh[c] = base[512 + (2 * wx + c) * 64 + lane];
            asm volatile("s_waitcnt lgkmcnt(0)" ::: "memory");
            __builtin_amdgcn_sched_barrier(0);
            __builtin_amdgcn_s_setprio(1);
            #pragma unroll
            for (int g = 0; g < 4; g++)
                #pragma unroll
                for (int c = 0; c < 2; c++)
                    acc[g][c] = __builtin_amdgcn_mfma_f32_32x32x16_f16(ah[g], bh[c], acc[g][c], 0, 0, 0);
            __builtin_amdgcn_s_setprio(0);
        }
    }
    {   // K-tile 7 (pb=1): no staging; tail waits 6/4/2/0
        #pragma unroll
        for (int p = 0; p < 4; p++) {
            if      (p == 0) asm volatile("s_waitcnt vmcnt(6)" ::: "memory");
            else if (p == 1) asm volatile("s_waitcnt vmcnt(4)" ::: "memory");
            else if (p == 2) asm volatile("s_waitcnt vmcnt(2)" ::: "memory");
            else             asm volatile("s_waitcnt vmcnt(0)" ::: "memory");
            __builtin_amdgcn_s_barrier();
            __builtin_amdgcn_sched_barrier(0);
            const half8* base = (const half8*)&smem[1][p * 1024];
            half8 ah[4], bh[2];
            #pragma unroll
            for (int g = 0; g < 4; g++) ah[g] = base[(4 * wy + g) * 64 + lane];
            #pragma unroll
            for (int c = 0; c < 2; c++) bh[c] = base[512 + (2 * wx + c) * 64 + lane];
            asm volatile("s_waitcnt lgkmcnt(0)" ::: "memory");
            __builtin_amdgcn_sched_barrier(0);
            __builtin_amdgcn_s_setprio(1);
            #pragma unroll
            for (int g = 0; g < 4; g++)
                #pragma unroll
                for (int c = 0; c < 2; c++)
                    acc[g][c] = __builtin_amdgcn_mfma_f32_32x32x16_f16(ah[g], bh[c], acc[g][c], 0, 0, 0);
            __builtin_amdgcn_s_setprio(0);
        }
    }

    const float wgt = (sym && bj > bi) ? 2.f : 1.f;

    // C/D layout (m74/m101): col=lane&31, row=(reg&3)+8*(reg>>2)+4*(lane>>5)
    const int fp = lane & 31, fh = lane >> 5;
    double s = 0.0;
    float dmin = 1e30f;
    {
        const float* rowN = &smN[128 * wy];
        const float* colN = &smN[BM2 + 64 * wx];
        const float kC = -0.0028177637517362567f;   // -log2(e)/512
        #pragma unroll
        for (int g = 0; g < 4; g++)
            #pragma unroll
            for (int c = 0; c < 2; c++) {
                float cn = colN[32 * c + fp];
                float rs = 0.f;
                #pragma unroll
                for (int r = 0; r < 16; r++) {
                    int r32 = (r & 3) + 8 * (r >> 2) + 4 * fh;
                    float d2 = rowN[32 * g + r32] + cn - 2.0f * acc[g][c][r];
                    dmin = fminf(dmin, d2);
                    rs += exp2f(d2 * kC);            // v_exp_f32; args in [-4.2,0]
                }
                s += (double)rs;
            }
        s *= (double)wgt;
    }

    #pragma unroll
    for (int off = 32; off > 0; off >>= 1) {
        s += __shfl_down(s, off);
        dmin = fminf(dmin, __shfl_down(dmin, off));
    }
    if (lane == 0) { wsum[wave] = s; wmin[wave] = dmin; }
    __syncthreads();
    if (tid == 0) {
        double ts = wsum[0];
        float  tm = wmin[0];
        #pragma unroll
        for (int w = 1; w < 8; w++) { ts += wsum[w]; tm = fminf(tm, wmin[w]); }
        atomicAdd(&accum[z], ts);
        if (z == 1)                              // noisy (+-~0.05) block min
            bmin[bi * gridDim.y + bj] = tm;
    }
}

__global__ __launch_bounds__(256)
void xy_gmin_kernel(const float* __restrict__ bmin, float* __restrict__ gmin, int nblk) {
    float m = 1e30f;
    for (int i = threadIdx.x; i < nblk; i += 256) m = fminf(m, bmin[i]);
    #pragma unroll
    for (int off = 32; off > 0; off >>= 1) m = fminf(m, __shfl_down(m, off));
    __shared__ float wm[4];
    if ((threadIdx.x & 63) == 0) wm[threadIdx.x >> 6] = m;
    __syncthreads();
    if (threadIdx.x == 0) gmin[0] = fminf(fminf(wm[0], wm[1]), fminf(wm[2], wm[3]));
}

// ---------- XY refine: R5-bit-exact bf16-split 3-product d2 min -----------
// 1024 threads / 16 waves; wave w owns row-group gy=w&3 (32 rows) and col
// groups 2*(w>>2), 2*(w>>2)+1. Per-accumulator k-chain (hh,hl,lh per kstep,
// ks 0..31) identical to R5 -> same d2 bits.
// Gate: bmin has 256x256 granularity (nbj cols of 256); this 128x256 tile
// is inside pair-block ((bi>>1), bj) -> gate on that entry. bmin[big] <=
// min over a SUPERSET of this tile's cells -> gate passes at least the old
// tile set -> identical final m (refine computes exact mins itself).
__global__ __launch_bounds__(1024)
void refine_min_kernel(const float* __restrict__ A, const float* __restrict__ B,
                       const float* __restrict__ An, const float* __restrict__ Bn,
                       const float* __restrict__ bmin, const float* __restrict__ gmin,
                       unsigned* __restrict__ minkey, int zidx, int nbj) {
    const int bi = blockIdx.x;
    const int bj = blockIdx.y;
    float bm = bmin[(bi >> 1) * nbj + bj];
    if (!(bm < gmin[0] + 0.5f)) return;
    const int row0 = bi * BTM, col0 = bj * BTN;

    __shared__ uint4 smem[1536];                 // Ahi|Alo|Bhi|Blo (R5 layout)
    __shared__ float smN[BTM + BTN];
    __shared__ float wmin[16];

    const int tid  = threadIdx.x;
    const int wave = tid >> 6, lane = tid & 63;
    const int gy = wave & 3, cg0 = 2 * (wave >> 2);
    if (tid < BTM) smN[tid] = An[row0 + tid];
    if (tid < BTN) smN[BTM + tid] = Bn[col0 + tid];

    const int fp = lane & 31, fh = lane >> 5;
    const int au = (32 * gy + fp) * 2 + fh;
    int bu[2];
    #pragma unroll
    for (int c = 0; c < 2; c++) bu[c] = (32 * (cg0 + c) + fp) * 2 + fh;

    f32x16 acc[2];
    #pragma unroll
    for (int c = 0; c < 2; c++)
        #pragma unroll
        for (int i = 0; i < 16; i++) acc[c][i] = 0.f;

    for (int ks = 0; ks < KSTEPS; ks++) {
        __syncthreads();                         // prev-step LDS reads done
        if (tid < 256) {                         // A: unit tid
            const float* s = A + (size_t)(row0 + (tid >> 1)) * D + ks * BK + (tid & 1) * 8;
            float v[8];
            *(float4*)&v[0] = *(const float4*)s;
            *(float4*)&v[4] = *(const float4*)(s + 4);
            uint4 hi, lo; split8(v, hi, lo);
            smem[AHI + tid] = hi; smem[ALO + tid] = lo;
        } else if (tid < 768) {                  // B: unit tid-256
            int u = tid - 256;
            const float* s = B + (size_t)(col0 + (u >> 1)) * D + ks * BK + (u & 1) * 8;
            float v[8];
            *(float4*)&v[0] = *(const float4*)s;
            *(float4*)&v[4] = *(const float4*)(s + 4);
            uint4 hi, lo; split8(v, hi, lo);
            smem[BHI + u] = hi; smem[BLO + u] = lo;
        }
        __syncthreads();
        {   // per-acc chain: hh, hl, lh (matches R5 acc[g][c] chain order)
            const short8* p = (const short8*)&smem[0];
            short8 ah = p[AHI + au], al = p[ALO + au];
            short8 bh[2], bl[2];
            #pragma unroll
            for (int c = 0; c < 2; c++) { bh[c] = p[BHI + bu[c]]; bl[c] = p[BLO + bu[c]]; }
            #pragma unroll
            for (int c = 0; c < 2; c++)
                acc[c] = __builtin_amdgcn_mfma_f32_32x32x16_bf16(ah, bh[c], acc[c], 0, 0, 0);
            #pragma unroll
            for (int c = 0; c < 2; c++)
                acc[c] = __builtin_amdgcn_mfma_f32_32x32x16_bf16(ah, bl[c], acc[c], 0, 0, 0);
            #pragma unroll
            for (int c = 0; c < 2; c++)
                acc[c] = __builtin_amdgcn_mfma_f32_32x32x16_bf16(al, bh[c], acc[c], 0, 0, 0);
        }
    }

    float dmin = 1e30f;
    const float* rowN = &smN[32 * gy];
    #pragma unroll
    for (int c = 0; c < 2; c++) {
        float cn = smN[BTM + 32 * (cg0 + c) + fp];
        #pragma unroll
        for (int r = 0; r < 16; r++) {
            int r32 = (r & 3) + 8 * (r >> 2) + 4 * fh;
            float d2 = rowN[r32] + cn - 2.0f * acc[c][r];
            dmin = fminf(dmin, d2);
        }
    }

    #pragma unroll
    for (int off = 32; off > 0; off >>= 1) dmin = fminf(dmin, __shfl_down(dmin, off));
    if (lane == 0) wmin[wave] = dmin;
    __syncthreads();
    if (tid == 0) {
        float m = wmin[0];
        #pragma unroll
        for (int w = 1; w < 16; w++) m = fminf(m, wmin[w]);
        atomicMin(&minkey[zidx], float_key(m));
    }
}

__global__ void finalize_kernel(const double* __restrict__ accum,
                                const unsigned* __restrict__ minkey,
                                float* __restrict__ out, int N, int M) {
    if (threadIdx.x == 0 && blockIdx.x == 0) {
        float Sp[3];
        #pragma unroll
        for (int z = 0; z < 3; z++) {
            float m = key_float(minkey[z]) * (-1.0f / 512.0f);
            double Sshift = accum[z] * exp(-(double)m);
            float r = (float)log(Sshift);        // correctly-rounded f32 log
            float lse = r + m;                   // fp32 add, as jax
            Sp[z] = (float)exp((double)lse);     // correctly-rounded f32 exp
        }
        float nf  = (float)N, mf = (float)M;
        float nn1 = (float)((double)N * (double)(N - 1));
        float mm1 = (float)((double)M * (double)(M - 1));
        float nm  = (float)((double)N * (double)M);
        float xx = (Sp[0] - nf) / nn1;
        float xy =  Sp[1]       / nm;
        float yy = (Sp[2] - mf) / mm1;
        out[0] = xx - 2.0f * xy + yy;
    }
}

extern "C" void kernel_launch(void* const* d_in, const int* in_sizes, int n_in,
                              void* d_out, int out_size, void* d_ws, size_t ws_size,
                              hipStream_t stream) {
    const float* X = (const float*)d_in[0];
    const float* Y = (const float*)d_in[1];
    const int N = in_sizes[0] / D;
    const int M = in_sizes[1] / D;
    const int gx  = N / BTM;                     // 64 (refine rows)
    const int gyR = M / BTN;                     // 32 (refine cols)
    const int gx2 = N / BM2;                     // 32 (pair rows)
    const int gy2 = M / BN2;                     // 32 (pair cols)

    double*   accum  = (double*)d_ws;
    unsigned* minkey = (unsigned*)((char*)d_ws + 32);
    float*    gmin   = (float*)((char*)d_ws + 48);
    float*    X2     = (float*)((char*)d_ws + 64);
    float*    Y2     = X2 + N;
    float*    bmin   = Y2 + M;
    size_t off = (64 + (size_t)(N + M) * 4 + (size_t)gx2 * gy2 * 4 + 255) & ~(size_t)255;
    size_t asz = (size_t)N * D * 2;
    uint4* Xh = (uint4*)((char*)d_ws + off);
    uint4* Yh = (uint4*)((char*)d_ws + off + asz);

    init_kernel<<<1, 64, 0, stream>>>(accum, minkey);

    row_norms_kernel<<<(N + M + 3) / 4, 256, 0, stream>>>(X, Y, X2, Y2, N, M);
    convert_h_kernel<<<dim3((N + 255) / 256, KSTEPS, 2), 256, 0, stream>>>(X, Y, Xh, Yh, N);

    diag_min_bits_kernel<<<N / 128 + M / 128, 256, 0, stream>>>(X, Y, X2, Y2, minkey, N / 128);

    dim3 grid(gx2, gy2, 3);
    pair_exp_sum_kernel<<<grid, 512, 0, stream>>>(Xh, Yh, X2, Y2, accum, bmin, N, M);

    xy_gmin_kernel<<<1, 256, 0, stream>>>(bmin, gmin, gx2 * gy2);
    refine_min_kernel<<<dim3(gx, gyR), 1024, 0, stream>>>(X, Y, X2, Y2, bmin, gmin,
                                                          minkey, 1, gy2);

    finalize_kernel<<<1, 64, 0, stream>>>(accum, minkey, (float*)d_out, N, M);
}

// Round 9
// 311.873 us; speedup vs baseline: 1.1272x; 1.1272x over previous
//
#include <hip/hip_runtime.h>
#include <math.h>

// MMD, Gaussian kernel, bandwidth=512. X:[8192,512] Y:[8192,512] fp32.
// S_AB = sum_ij exp(-||a_i-b_j||^2/512); final combine emulates the
// reference's fp32 logsumexp->exp->combine path (see finalize_kernel).
//
// Architecture (validated R9-R11): fp16 single-product MFMA S-pass (S needs
// << 1 fp32 lse cell) + bit-exact R5 bf16-split 3-product d2 min for m
// (XX/YY via 32x32 diag self-tiles, XY via banded refine).
// PAIR-KERNEL HISTORY: 128x128 / 4 waves of 64x64 / A+B DMA-staged is the
// proven structure (R15: 180us, MfmaUtil 37%). Sync-structure variants all
// land 177-186us (2-barrier dbuf, 1-barrier 3-buf); mixed reg-load+DMA
// counted windows race (R16/17 NaN: vmcnt completion order across op
// classes unordered); 256^2 8-phase port REGRESSED (R20: 238us - per-phase
// vmcnt + 1 blk/CU serializes). Conclusion: 128^2 structure is at its
// documented ~36% structural ceiling; pair kernel frozen at R15's best.
// Round-21 (this): consolidation. (1) pair reverted to R15's exact proven
// kernel. (2) Non-pair residual (total-pair) has been stable 113-136us >>
// sum of estimated kernel times (~35us) -> suspect launch/serialization
// overhead of 8 dependent kernels. Cut 2 launches: init fused into
// row_norms (block 0); xy_gmin folded into refine (every block redundantly
// reduces bmin - deterministic same-order fminf -> identical gate bits).

#define D      512
#define BTM    128
#define BTN    256   // refine-kernel tile
#define BTNP   128   // pair-kernel tile cols
#define BK     16
#define KSTEPS (D / BK)

// 16B-unit offsets in the XY refine kernel's LDS (R5 layout [point*2+khalf])
#define AHI 0
#define ALO 256
#define BHI 512
#define BLO 1024

typedef _Float16 half8 __attribute__((ext_vector_type(8)));
typedef __attribute__((ext_vector_type(8)))  short  short8;   // 8 bf16
typedef __attribute__((ext_vector_type(16))) float  f32x16;   // 32x32 acc

union U4H8 { uint4 u; half8 h; };
union U4S8 { uint4 u; short8 s; };

__device__ __forceinline__ unsigned short bf16_rne(float x) {
    unsigned u = __float_as_uint(x);
    return (unsigned short)((u + 0x7fffu + ((u >> 16) & 1u)) >> 16);
}
__device__ __forceinline__ float bf16_f32(unsigned short b) {
    return __uint_as_float(((unsigned)b) << 16);
}
__device__ __forceinline__ void split8(const float v[8], uint4& hi, uint4& lo) {
    unsigned h[8], l[8];
    #pragma unroll
    for (int j = 0; j < 8; j++) {
        unsigned short bh = bf16_rne(v[j]);
        float r = v[j] - bf16_f32(bh);          // exact (Sterbenz)
        unsigned short bl = bf16_rne(r);
        h[j] = bh; l[j] = bl;
    }
    hi.x = h[0] | (h[1] << 16); hi.y = h[2] | (h[3] << 16);
    hi.z = h[4] | (h[5] << 16); hi.w = h[6] | (h[7] << 16);
    lo.x = l[0] | (l[1] << 16); lo.y = l[2] | (l[3] << 16);
    lo.z = l[4] | (l[5] << 16); lo.w = l[6] | (l[7] << 16);
}

// async global->LDS, 16B per lane
__device__ __forceinline__ void lds16(const uint4* g, uint4* l) {
    __builtin_amdgcn_global_load_lds(
        (const __attribute__((address_space(1))) void*)g,
        (__attribute__((address_space(3))) void*)(unsigned int)(uintptr_t)(void*)l,
        16, 0, 0);
}

// fp16 convert: src[npts][512] fp32 -> [kstep][p>>5][khalf][p&31] 16B units
__global__ __launch_bounds__(256)
void convert_h_kernel(const float* __restrict__ X, const float* __restrict__ Y,
                      uint4* __restrict__ Xh, uint4* __restrict__ Yh, int npts) {
    const float* src = blockIdx.z ? Y : X;
    uint4*       dst = blockIdx.z ? Yh : Xh;
    const int ks = blockIdx.y;
    const int p  = blockIdx.x * 256 + threadIdx.x;
    if (p >= npts) return;
    const float* s = src + (size_t)p * D + ks * BK;
    float v[16];
    *(float4*)&v[0]  = *(const float4*)(s);
    *(float4*)&v[4]  = *(const float4*)(s + 4);
    *(float4*)&v[8]  = *(const float4*)(s + 8);
    *(float4*)&v[12] = *(const float4*)(s + 12);
    U4H8 a, b;
    #pragma unroll
    for (int j = 0; j < 8; j++) { a.h[j] = (_Float16)v[j]; b.h[j] = (_Float16)v[8 + j]; }
    size_t u = (size_t)ks * npts * 2 + (size_t)(p >> 5) * 64 + (p & 31);
    dst[u] = a.u; dst[u + 32] = b.u;
}

// row norms + fused init (block 0 initializes accum/minkey; consumers are
// in later kernels -> stream order suffices, no sync needed here)
__global__ __launch_bounds__(256)
void row_norms_kernel(const float* __restrict__ X, const float* __restrict__ Y,
                      float* __restrict__ X2, float* __restrict__ Y2, int N, int M,
                      double* __restrict__ accum, unsigned* __restrict__ minkey) {
    if (blockIdx.x == 0) {
        if (threadIdx.x < 3) accum[threadIdx.x] = 0.0;
        if (threadIdx.x < 4) minkey[threadIdx.x] = 0xFFFFFFFFu;
    }
    const int wave = threadIdx.x >> 6;
    const int lane = threadIdx.x & 63;
    const int row  = blockIdx.x * 4 + wave;
    const float* src; float* dst; int r;
    if (row < N)          { src = X; dst = X2; r = row; }
    else if (row < N + M) { src = Y; dst = Y2; r = row - N; }
    else return;
    const float* p = src + (size_t)r * D;
    float s = 0.f;
    #pragma unroll
    for (int c = 0; c < D; c += 64) {
        float v = p[c + lane];
        s = fmaf(v, v, s);
    }
    #pragma unroll
    for (int off = 32; off > 0; off >>= 1) s += __shfl_down(s, off);
    if (lane == 0) dst[r] = s;
}

__device__ inline unsigned float_key(float f) {
    unsigned u = __float_as_uint(f);
    return (u & 0x80000000u) ? ~u : (u | 0x80000000u);
}
__device__ inline float key_float(unsigned k) {
    return __uint_as_float((k & 0x80000000u) ? (k ^ 0x80000000u) : ~k);
}

// ---- XX/YY m: R5-bit-exact diag d2 via 32x32 self-tiles (fused X+Y) ------
__global__ __launch_bounds__(256)
void diag_min_bits_kernel(const float* __restrict__ X, const float* __restrict__ Y,
                          const float* __restrict__ X2, const float* __restrict__ Y2,
                          unsigned* __restrict__ minkey, int ngx) {
    int b = blockIdx.x;
    const float *src, *n2; int zidx;
    if (b < ngx) { src = X; n2 = X2; zidx = 0; }
    else         { src = Y; n2 = Y2; zidx = 2; b -= ngx; }

    const int tid  = threadIdx.x;
    const int wave = tid >> 6, lane = tid & 63;
    const int grp  = b * 4 + wave;                // 32-point group id
    const int fp   = lane & 31, fh = lane >> 5;
    const int pt   = grp * 32 + fp;
    const float* s = src + (size_t)pt * D + fh * 8;

    f32x16 acc;
    #pragma unroll
    for (int i = 0; i < 16; i++) acc[i] = 0.f;

    for (int ks = 0; ks < KSTEPS; ks++) {
        float v[8];
        *(float4*)&v[0] = *(const float4*)(s + ks * BK);
        *(float4*)&v[4] = *(const float4*)(s + ks * BK + 4);
        U4S8 hi, lo;
        split8(v, hi.u, lo.u);
        short8 ah = hi.s, al = lo.s;
        // R5 order: hh, h*lB, lA*h (A-frag == B-frag here)
        acc = __builtin_amdgcn_mfma_f32_32x32x16_bf16(ah, ah, acc, 0, 0, 0);
        acc = __builtin_amdgcn_mfma_f32_32x32x16_bf16(ah, al, acc, 0, 0, 0);
        acc = __builtin_amdgcn_mfma_f32_32x32x16_bf16(al, ah, acc, 0, 0, 0);
    }

    float dmin = 1e30f;
    if (fh == ((fp >> 2) & 1)) {
        int r = (fp & 3) + 4 * (fp >> 3);
        float av = acc[r];
        float rn = n2[pt];
        float cn = rn;
        float d2 = rn + cn - 2.0f * av;           // exact: contraction-safe
        dmin = d2;
    }
    #pragma unroll
    for (int off = 32; off > 0; off >>= 1) dmin = fminf(dmin, __shfl_down(dmin, off));
    __shared__ float wm[4];
    __shared__ int   wz[4];
    if (lane == 0) { wm[wave] = dmin; wz[wave] = zidx; }
    __syncthreads();
    if (tid == 0)
        atomicMin(&minkey[wz[0]],
                  float_key(fminf(fminf(wm[0], wm[1]), fminf(wm[2], wm[3]))));
}

// ---------- fp16 S-pass: grid (64,64,3): z=0 XX (sym), 1 XY, 2 YY ----------
// R15's proven kernel: 128x128 block tile, 4 waves (2x2) of 64x64 -> 64 acc
// regs, 4 waves/SIMD. A+B DMA-staged; per 2-kstep buffer [kstep j][A|B]
// (1024 uint4 = 16 KB); 2 bufs = 32 KB. Counted-vmcnt: each iteration
// issues exactly 4 DMAs/wave (homogeneous window) -> vmcnt(4).
__global__ __launch_bounds__(256, 4)
void pair_exp_sum_kernel(const uint4* __restrict__ Xh, const uint4* __restrict__ Yh,
                         const float* __restrict__ X2, const float* __restrict__ Y2,
                         double* __restrict__ accum, float* __restrict__ bmin,
                         int N, int M) {
    const int z = blockIdx.z;
    const uint4 *Ah, *Bh; const float *An, *Bn; bool sym; int na, nb;
    if (z == 0)      { Ah = Xh; Bh = Xh; An = X2; Bn = X2; sym = true;  na = N; nb = N; }
    else if (z == 1) { Ah = Xh; Bh = Yh; An = X2; Bn = Y2; sym = false; na = N; nb = M; }
    else             { Ah = Yh; Bh = Yh; An = Y2; Bn = Y2; sym = true;  na = M; nb = M; }
    const int bi = blockIdx.x, bj = blockIdx.y;
    if (sym && bj < bi) return;                  // whole block below diagonal

    __shared__ uint4  smem[2][1024];             // 2 bufs x 16 KB (2 ksteps each)
    __shared__ float  smN[BTM + BTNP];
    __shared__ double wsum[4];
    __shared__ float  wmin[4];

    const int tid  = threadIdx.x;
    const int wave = tid >> 6, lane = tid & 63;
    const int wy = wave >> 1, wx = wave & 1;     // 2x2 waves, each 64x64
    const int row0 = bi * BTM, col0 = bj * BTNP;

    if (tid < BTM) smN[tid] = An[row0 + tid];
    else           smN[tid] = Bn[col0 + tid - BTM];

    const size_t strideA = (size_t)na * 2;       // 16B units per kstep
    const size_t strideB = (size_t)nb * 2;
    // stage-role of this wave: kstep-within-pair sj, kind (0=A rows, 1=B cols)
    const int sj = wave >> 1, skind = wave & 1;
    const uint4* gS = (skind ? Bh + (size_t)(col0 >> 5) * 64
                             : Ah + (size_t)(row0 >> 5) * 64) + lane;
    const size_t strideS = skind ? strideB : strideA;

    f32x16 acc[2][2];
    #pragma unroll
    for (int g = 0; g < 2; g++)
        #pragma unroll
        for (int c = 0; c < 2; c++)
            #pragma unroll
            for (int i = 0; i < 16; i++) acc[g][c][i] = 0.f;

    // stage TWO k-steps into one buffer; kstep j at unit j*512: A@0, B@256.
    // Each wave loads its 256-unit chunk (4 x 64-unit segments) -> 4 DMAs.
    auto stage2 = [&](int buf, int ks) {
        const uint4* g = gS + (size_t)(ks + sj) * strideS;
        uint4* d = &smem[buf][sj * 512 + skind * 256 + lane];
        #pragma unroll
        for (int t = 0; t < 4; t++)
            lds16(g + t * 64, d + t * 64);
    };
    auto computeK = [&](const uint4* base) {     // one kstep: A@0, B@256
        const half8* p = (const half8*)base;
        half8 ah[2], bh[2];
        #pragma unroll
        for (int g = 0; g < 2; g++) ah[g] = p[(2 * wy + g) * 64 + lane];
        #pragma unroll
        for (int c = 0; c < 2; c++) bh[c] = p[256 + (2 * wx + c) * 64 + lane];
        #pragma unroll
        for (int g = 0; g < 2; g++)
            #pragma unroll
            for (int c = 0; c < 2; c++)
                acc[g][c] = __builtin_amdgcn_mfma_f32_32x32x16_f16(ah[g], bh[c], acc[g][c], 0, 0, 0);
    };

    // Counted-vmcnt schedule. Window invariant: each iteration issues exactly
    // 4 DMA ops per wave ("memory"-fenced) -> at s_waitcnt vmcnt(4) the
    // previous window's 4 are the FIFO-oldest outstanding, so they (and only
    // they) are drained. Current window's prefetch stays in flight across
    // both barriers.
    stage2(0, 0);

    #pragma unroll
    for (int it = 1; it < KSTEPS / 2; it++) {    // 15 intervals
        stage2(it & 1, 2 * it);                  // prefetch next pair (4 DMA)
        asm volatile("s_waitcnt vmcnt(4)" ::: "memory");    // prev pair landed (self)
        __builtin_amdgcn_s_barrier();                       // ... for all waves
        __builtin_amdgcn_sched_barrier(0);                  // pin ds_reads below
        const int pb = (it - 1) & 1;
        computeK(&smem[pb][0]);                  // ksteps 2(it-1), 2(it-1)+1
        computeK(&smem[pb][512]);
        asm volatile("s_waitcnt lgkmcnt(0)" ::: "memory");  // my ds_reads retired
        __builtin_amdgcn_s_barrier();                       // buffer pb free for all
    }
    asm volatile("s_waitcnt vmcnt(0)" ::: "memory");        // last pair landed
    __builtin_amdgcn_s_barrier();
    __builtin_amdgcn_sched_barrier(0);
    computeK(&smem[1][0]);                       // ksteps 30, 31
    computeK(&smem[1][512]);

    const float wgt = (sym && bj > bi) ? 2.f : 1.f;

    // C/D layout (m74/m101): col=lane&31, row=(reg&3)+8*(reg>>2)+4*(lane>>5)
    const int fp = lane & 31, fh = lane >> 5;
    double s = 0.0;
    float dmin = 1e30f;
    {
        const float* rowN = &smN[64 * wy];
        const float* colN = &smN[BTM + 64 * wx];
        const float kC = -0.0028177637517362567f;   // -log2(e)/512
        #pragma unroll
        for (int g = 0; g < 2; g++)
            #pragma unroll
            for (int c = 0; c < 2; c++) {
                float cn = colN[32 * c + fp];
                float rs = 0.f;
                #pragma unroll
                for (int r = 0; r < 16; r++) {
                    int r32 = (r & 3) + 8 * (r >> 2) + 4 * fh;
                    float d2 = rowN[32 * g + r32] + cn - 2.0f * acc[g][c][r];
                    dmin = fminf(dmin, d2);
                    rs += exp2f(d2 * kC);            // v_exp_f32; args in [-4.2,0]
                }
                s += (double)rs;
            }
        s *= (double)wgt;
    }

    #pragma unroll
    for (int off = 32; off > 0; off >>= 1) {
        s += __shfl_down(s, off);
        dmin = fminf(dmin, __shfl_down(dmin, off));
    }
    if (lane == 0) { wsum[wave] = s; wmin[wave] = dmin; }
    __syncthreads();
    if (tid == 0) {
        atomicAdd(&accum[z], wsum[0] + wsum[1] + wsum[2] + wsum[3]);
        if (z == 1)                              // noisy (+-~0.05) block min
            bmin[bi * gridDim.y + bj] = fminf(fminf(wmin[0], wmin[1]),
                                              fminf(wmin[2], wmin[3]));
    }
}

// ---------- XY refine: R5-bit-exact bf16-split 3-product d2 min -----------
// 1024 threads / 16 waves; wave w owns row-group gy=w&3 (32 rows) and col
// groups 2*(w>>2), 2*(w>>2)+1. Per-accumulator k-chain (hh,hl,lh per kstep,
// ks 0..31) identical to R5 -> same d2 bits.
// gmin is computed HERE (xy_gmin kernel folded in): every block reduces the
// full bmin array in the same order -> identical float result in all blocks
// -> identical, uniform gate decisions. Gate: bmin has 128-col granularity;
// this 256-col tile covers entries (bi,2bj),(bi,2bj+1) -> min of the two.
__global__ __launch_bounds__(1024)
void refine_min_kernel(const float* __restrict__ A, const float* __restrict__ B,
                       const float* __restrict__ An, const float* __restrict__ Bn,
                       const float* __restrict__ bmin,
                       unsigned* __restrict__ minkey, int zidx, int nbj, int nblk) {
    const int bi = blockIdx.x;
    const int bj = blockIdx.y;
    const int tid  = threadIdx.x;
    const int wave = tid >> 6, lane = tid & 63;

    __shared__ uint4 smem[1536];                 // Ahi|Alo|Bhi|Blo (R5 layout)
    __shared__ float smN[BTM + BTN];
    __shared__ float wmin[16];
    __shared__ float wgm[16];

    // block-local gmin over all bmin entries (deterministic order)
    float gm = 1e30f;
    for (int i = tid; i < nblk; i += 1024) gm = fminf(gm, bmin[i]);
    #pragma unroll
    for (int off = 32; off > 0; off >>= 1) gm = fminf(gm, __shfl_down(gm, off));
    if (lane == 0) wgm[wave] = gm;
    __syncthreads();
    float g0 = wgm[0];
    #pragma unroll
    for (int w = 1; w < 16; w++) g0 = fminf(g0, wgm[w]);

    float bm = fminf(bmin[bi * nbj + 2 * bj], bmin[bi * nbj + 2 * bj + 1]);
    if (!(bm < g0 + 0.5f)) return;               // uniform across block
    const int row0 = bi * BTM, col0 = bj * BTN;

    const int gy = wave & 3, cg0 = 2 * (wave >> 2);
    if (tid < BTM) smN[tid] = An[row0 + tid];
    if (tid < BTN) smN[BTM + tid] = Bn[col0 + tid];

    const int fp = lane & 31, fh = lane >> 5;
    const int au = (32 * gy + fp) * 2 + fh;
    int bu[2];
    #pragma unroll
    for (int c = 0; c < 2; c++) bu[c] = (32 * (cg0 + c) + fp) * 2 + fh;

    f32x16 acc[2];
    #pragma unroll
    for (int c = 0; c < 2; c++)
        #pragma unroll
        for (int i = 0; i < 16; i++) acc[c][i] = 0.f;

    for (int ks = 0; ks < KSTEPS; ks++) {
        __syncthreads();                         // prev-step LDS reads done
        if (tid < 256) {                         // A: unit tid
            const float* s = A + (size_t)(row0 + (tid >> 1)) * D + ks * BK + (tid & 1) * 8;
            float v[8];
            *(float4*)&v[0] = *(const float4*)s;
            *(float4*)&v[4] = *(const float4*)(s + 4);
            uint4 hi, lo; split8(v, hi, lo);
            smem[AHI + tid] = hi; smem[ALO + tid] = lo;
        } else if (tid < 768) {                  // B: unit tid-256
            int u = tid - 256;
            const float* s = B + (size_t)(col0 + (u >> 1)) * D + ks * BK + (u & 1) * 8;
            float v[8];
            *(float4*)&v[0] = *(const float4*)s;
            *(float4*)&v[4] = *(const float4*)(s + 4);
            uint4 hi, lo; split8(v, hi, lo);
            smem[BHI + u] = hi; smem[BLO + u] = lo;
        }
        __syncthreads();
        {   // per-acc chain: hh, hl, lh (matches R5 acc[g][c] chain order)
            const short8* p = (const short8*)&smem[0];
            short8 ah = p[AHI + au], al = p[ALO + au];
            short8 bh[2], bl[2];
            #pragma unroll
            for (int c = 0; c < 2; c++) { bh[c] = p[BHI + bu[c]]; bl[c] = p[BLO + bu[c]]; }
            #pragma unroll
            for (int c = 0; c < 2; c++)
                acc[c] = __builtin_amdgcn_mfma_f32_32x32x16_bf16(ah, bh[c], acc[c], 0, 0, 0);
            #pragma unroll
            for (int c = 0; c < 2; c++)
                acc[c] = __builtin_amdgcn_mfma_f32_32x32x16_bf16(ah, bl[c], acc[c], 0, 0, 0);
            #pragma unroll
            for (int c = 0; c < 2; c++)
                acc[c] = __builtin_amdgcn_mfma_f32_32x32x16_bf16(al, bh[c], acc[c], 0, 0, 0);
        }
    }

    float dmin = 1e30f;
    const float* rowN = &smN[32 * gy];
    #pragma unroll
    for (int c = 0; c < 2; c++) {
        float cn = smN[BTM + 32 * (cg0 + c) + fp];
        #pragma unroll
        for (int r = 0; r < 16; r++) {
            int r32 = (r & 3) + 8 * (r >> 2) + 4 * fh;
            float d2 = rowN[r32] + cn - 2.0f * acc[c][r];
            dmin = fminf(dmin, d2);
        }
    }

    #pragma unroll
    for (int off = 32; off > 0; off >>= 1) dmin = fminf(dmin, __shfl_down(dmin, off));
    if (lane == 0) wmin[wave] = dmin;
    __syncthreads();
    if (tid == 0) {
        float m = wmin[0];
        #pragma unroll
        for (int w = 1; w < 16; w++) m = fminf(m, wmin[w]);
        atomicMin(&minkey[zidx], float_key(m));
    }
}

__global__ void finalize_kernel(const double* __restrict__ accum,
                                const unsigned* __restrict__ minkey,
                                float* __restrict__ out, int N, int M) {
    if (threadIdx.x == 0 && blockIdx.x == 0) {
        float Sp[3];
        #pragma unroll
        for (int z = 0; z < 3; z++) {
            float m = key_float(minkey[z]) * (-1.0f / 512.0f);
            double Sshift = accum[z] * exp(-(double)m);
            float r = (float)log(Sshift);        // correctly-rounded f32 log
            float lse = r + m;                   // fp32 add, as jax
            Sp[z] = (float)exp((double)lse);     // correctly-rounded f32 exp
        }
        float nf  = (float)N, mf = (float)M;
        float nn1 = (float)((double)N * (double)(N - 1));
        float mm1 = (float)((double)M * (double)(M - 1));
        float nm  = (float)((double)N * (double)M);
        float xx = (Sp[0] - nf) / nn1;
        float xy =  Sp[1]       / nm;
        float yy = (Sp[2] - mf) / mm1;
        out[0] = xx - 2.0f * xy + yy;
    }
}

extern "C" void kernel_launch(void* const* d_in, const int* in_sizes, int n_in,
                              void* d_out, int out_size, void* d_ws, size_t ws_size,
                              hipStream_t stream) {
    const float* X = (const float*)d_in[0];
    const float* Y = (const float*)d_in[1];
    const int N = in_sizes[0] / D;
    const int M = in_sizes[1] / D;
    const int gx  = N / BTM;                     // 64
    const int gyP = M / BTNP;                    // 64 (pair kernel cols)
    const int gyR = M / BTN;                     // 32 (refine cols)

    double*   accum  = (double*)d_ws;
    unsigned* minkey = (unsigned*)((char*)d_ws + 32);
    float*    X2     = (float*)((char*)d_ws + 64);
    float*    Y2     = X2 + N;
    float*    bmin   = Y2 + M;
    size_t off = (64 + (size_t)(N + M) * 4 + (size_t)gx * gyP * 4 + 255) & ~(size_t)255;
    size_t asz = (size_t)N * D * 2;
    uint4* Xh = (uint4*)((char*)d_ws + off);
    uint4* Yh = (uint4*)((char*)d_ws + off + asz);

    row_norms_kernel<<<(N + M + 3) / 4, 256, 0, stream>>>(X, Y, X2, Y2, N, M,
                                                          accum, minkey);
    convert_h_kernel<<<dim3((N + 255) / 256, KSTEPS, 2), 256, 0, stream>>>(X, Y, Xh, Yh, N);

    diag_min_bits_kernel<<<N / 128 + M / 128, 256, 0, stream>>>(X, Y, X2, Y2, minkey, N / 128);

    dim3 grid(gx, gyP, 3);
    pair_exp_sum_kernel<<<grid, 256, 0, stream>>>(Xh, Yh, X2, Y2, accum, bmin, N, M);

    refine_min_kernel<<<dim3(gx, gyR), 1024, 0, stream>>>(X, Y, X2, Y2, bmin,
                                                          minkey, 1, gyP, gx * gyP);

    finalize_kernel<<<1, 64, 0, stream>>>(accum, minkey, (float*)d_out, N, M);
}